// Round 3
// baseline (7098.909 us; speedup 1.0000x reference)
//
#include <hip/hip_runtime.h>
#include <hip/hip_fp16.h>
#include <math.h>

#define Tt 64
#define Bb 16
#define Nn 256
#define Ww 64
#define Rr 4
#define INd 64
#define OUTd 64
#define IFS 471
#define EPSf 1e-6f

// packed half2 weight layout offsets (in half2 units)
#define W1OFF   0        // 160*256
#define W2OFF   40960    // 128*256
#define WIFOFF  73728    // 128*471
#define WOUTOFF 134016   // 128*64
#define WMEMOFF 142208   // 128*64
#define WTOT    150400

__device__ __forceinline__ float sigm(float x) { return 1.f / (1.f + expf(-x)); }
__device__ __forceinline__ float oneplus_(float x) {
    return 1.f + fmaxf(x, 0.f) + log1pf(expf(-fabsf(x)));
}

// ---- converter: fp32 weights -> packed half2 (pairs along K) ----
__global__ void convert_weights(const float* __restrict__ W1, const float* __restrict__ W2,
                                const float* __restrict__ Wif, const float* __restrict__ Wout,
                                const float* __restrict__ Wmem, __half2* __restrict__ wp) {
    int i = blockIdx.x * blockDim.x + threadIdx.x;
    if (i >= WTOT) return;
    float a, b;
    if (i < W2OFF)        { int r = i;           int k2 = r >> 8, n = r & 255; a = W1[(2*k2)*256+n];  b = W1[(2*k2+1)*256+n]; }
    else if (i < WIFOFF)  { int r = i - W2OFF;   int k2 = r >> 8, n = r & 255; a = W2[(2*k2)*256+n];  b = W2[(2*k2+1)*256+n]; }
    else if (i < WOUTOFF) { int r = i - WIFOFF;  int k2 = r / IFS, o = r - IFS*k2; a = Wif[(2*k2)*IFS+o]; b = Wif[(2*k2+1)*IFS+o]; }
    else if (i < WMEMOFF) { int r = i - WOUTOFF; int k2 = r >> 6, n = r & 63;  a = Wout[(2*k2)*64+n]; b = Wout[(2*k2+1)*64+n]; }
    else                  { int r = i - WMEMOFF; int k2 = r >> 6, n = r & 63;  a = Wmem[(2*k2)*64+n]; b = Wmem[(2*k2+1)*64+n]; }
    wp[i] = __floats2half2_rn(a, b);
}

// One block (1024 threads, 16 waves) per batch element; whole T=64 scan inside.
__global__ __launch_bounds__(1024) void dnc_kernel(
    const float* __restrict__ x, const float* __restrict__ b1,
    const float* __restrict__ b2, const float* __restrict__ bif,
    const __half2* __restrict__ wp,
    __half* __restrict__ memg,   // per batch 64*256 halves
    __half* __restrict__ linkg,  // per batch 256*256 halves
    float* __restrict__ out)
{
    const int b = blockIdx.x;
    const int tid = threadIdx.x;
    const int lane = tid & 63;
    const int wv = tid >> 6;
    const int q = tid >> 8;        // quarter 0..3
    const int n8 = tid & 255;
    const int rr = q;
    const int nq = tid >> 2, cq = tid & 3;   // GEMV1/2 map
    const int o3 = tid >> 1, c3 = tid & 1;   // GEMV3 map
    const int o4 = tid >> 4, c4 = tid & 15;  // out-GEMV map

    __half*  memh  = memg + (size_t)b * (Ww * Nn);
    __half2* memh2 = (__half2*)memh;
    __half*  linkh = linkg + (size_t)b * (Nn * Nn);
    __half2* linkh2 = (__half2*)linkh;

    __shared__ float s_lp[4][256][5];
    __shared__ float s_ssp[4][256];
    __shared__ float s_part[1024];
    __shared__ __align__(16) float s_ctrl[320];
    __shared__ __align__(16) float s_h[256];
    __shared__ __align__(16) float s_nn[256];
    __shared__ float s_z[472];
    __shared__ float s_usage[256], s_ww[256], s_prec[256];
    __shared__ __align__(16) float s_sorted[256];
    __shared__ __align__(16) float s_cp[256];
    __shared__ int   s_rank[256];
    __shared__ __align__(16) float s_rw[256][4];
    __shared__ __align__(16) float s_rvec[256];
    __shared__ float s_rkeyn[256];
    __shared__ float s_wkeyn[64], s_erase[64], s_wvec[64];
    __shared__ float s_fg[4], s_rstr[4], s_knorm[4], s_rmode[3][4], s_sc[4];
    __shared__ float s_red[32];

    // ---- persistent register weights (valid whole launch) ----
    __half2 w1r[40];
#pragma unroll
    for (int j = 0; j < 40; ++j) w1r[j] = wp[W1OFF + (cq*40 + j)*256 + nq];
    __half2 w2r[32];
#pragma unroll
    for (int j = 0; j < 32; ++j) w2r[j] = wp[W2OFF + (cq*32 + j)*256 + nq];
    const float b1r = b1[nq], b2r = b2[nq];
    const float bifr = (o3 < IFS) ? bif[o3] : 0.f;

    // ---- state init (ws poisoned before every launch) ----
    {
        __half2 e2 = __floats2half2_rn(EPSf, EPSf);
#pragma unroll
        for (int j = 0; j < 8; ++j) memh2[tid + j*1024] = e2;
        __half2 z2 = __floats2half2_rn(0.f, 0.f);
#pragma unroll
        for (int j = 0; j < 32; ++j) linkh2[tid + j*1024] = z2;
    }
    if (tid < 256) {
        s_usage[tid] = 0.f; s_ww[tid] = 0.f; s_prec[tid] = 0.f; s_rvec[tid] = 0.f;
        s_rw[tid][0] = 0.f; s_rw[tid][1] = 0.f; s_rw[tid][2] = 0.f; s_rw[tid][3] = 0.f;
    }
    if (tid < 64) s_ctrl[tid] = x[b * INd + tid];
    else if (tid < 320) s_ctrl[tid] = 0.f;

    const float4* rw4 = (const float4*)s_rw;

    for (int t = 0; t < Tt; ++t) {
        __syncthreads();  // B0

        // ---- GEMV1: h = tanh(ctrl @ W1 + b1); reg weights, 4-lane K-split ----
        {
            float a0 = 0.f, a1 = 0.f, a2 = 0.f, a3 = 0.f;
#pragma unroll
            for (int j = 0; j < 40; j += 2) {
                float2 f0 = __half22float2(w1r[j]);
                float2 f1 = __half22float2(w1r[j+1]);
                float2 c0 = *(const float2*)&s_ctrl[(cq*40 + j)*2];
                float2 c1 = *(const float2*)&s_ctrl[(cq*40 + j + 1)*2];
                a0 = fmaf(c0.x, f0.x, a0); a1 = fmaf(c0.y, f0.y, a1);
                a2 = fmaf(c1.x, f1.x, a2); a3 = fmaf(c1.y, f1.y, a3);
            }
            float v = (a0 + a1) + (a2 + a3);
            v += __shfl_xor(v, 1, 64); v += __shfl_xor(v, 2, 64);
            if (cq == 0) s_h[nq] = tanhf(b1r + v);
        }
        __syncthreads();  // B1

        // ---- GEMV2: nn = tanh(h @ W2 + b2) ----
        {
            float a0 = 0.f, a1 = 0.f, a2 = 0.f, a3 = 0.f;
#pragma unroll
            for (int j = 0; j < 32; j += 2) {
                float2 f0 = __half22float2(w2r[j]);
                float2 f1 = __half22float2(w2r[j+1]);
                float2 c0 = *(const float2*)&s_h[(cq*32 + j)*2];
                float2 c1 = *(const float2*)&s_h[(cq*32 + j + 1)*2];
                a0 = fmaf(c0.x, f0.x, a0); a1 = fmaf(c0.y, f0.y, a1);
                a2 = fmaf(c1.x, f1.x, a2); a3 = fmaf(c1.y, f1.y, a3);
            }
            float v = (a0 + a1) + (a2 + a3);
            v += __shfl_xor(v, 1, 64); v += __shfl_xor(v, 2, 64);
            if (cq == 0) s_nn[nq] = tanhf(b2r + v);
        }
        __syncthreads();  // B2

        // ---- GEMV3: z = nn @ W_if + b_if; streamed fp16, 2-lane K-split ----
        {
            float v = 0.f;
            if (o3 < IFS) {
                const __half2* wif = wp + WIFOFF + c3*64*IFS + o3;
                float a0=0,a1=0,a2=0,a3=0,a4=0,a5=0,a6=0,a7=0;
#pragma unroll
                for (int j = 0; j < 64; j += 4) {
                    __half2 h0 = wif[(j+0)*IFS];
                    __half2 h1 = wif[(j+1)*IFS];
                    __half2 h2 = wif[(j+2)*IFS];
                    __half2 h3 = wif[(j+3)*IFS];
                    float2 s0 = *(const float2*)&s_nn[(c3*64 + j + 0)*2];
                    float2 s1 = *(const float2*)&s_nn[(c3*64 + j + 1)*2];
                    float2 s2 = *(const float2*)&s_nn[(c3*64 + j + 2)*2];
                    float2 s3 = *(const float2*)&s_nn[(c3*64 + j + 3)*2];
                    float2 f0 = __half22float2(h0), f1 = __half22float2(h1);
                    float2 f2 = __half22float2(h2), f3 = __half22float2(h3);
                    a0 = fmaf(s0.x, f0.x, a0); a1 = fmaf(s0.y, f0.y, a1);
                    a2 = fmaf(s1.x, f1.x, a2); a3 = fmaf(s1.y, f1.y, a3);
                    a4 = fmaf(s2.x, f2.x, a4); a5 = fmaf(s2.y, f2.y, a5);
                    a6 = fmaf(s3.x, f3.x, a6); a7 = fmaf(s3.y, f3.y, a7);
                }
                v = ((a0+a1)+(a2+a3)) + ((a4+a5)+(a6+a7));
            }
            v += __shfl_xor(v, 1, 64);
            if (c3 == 0 && o3 < IFS) s_z[o3] = bifr + v;
        }
        __syncthreads();  // B3

        // ---- parse scalars ----
        if (tid < Rr) {
            float ss = 0.f;
            for (int w = 0; w < Ww; ++w) { float v = s_z[w*Rr + tid]; ss = fmaf(v, v, ss); }
            s_knorm[tid] = sqrtf(ss) + EPSf;
            s_rstr[tid] = oneplus_(s_z[256 + tid]);
            s_fg[tid] = sigm(s_z[453 + tid]);
            float a = s_z[459 + tid], bm = s_z[463 + tid], c = s_z[467 + tid];
            float mx = fmaxf(a, fmaxf(bm, c));
            float ea = expf(a - mx), eb = expf(bm - mx), ec = expf(c - mx);
            float inv = 1.f / ((ea + eb) + ec);
            s_rmode[0][tid] = ea * inv; s_rmode[1][tid] = eb * inv; s_rmode[2][tid] = ec * inv;
        } else if (tid == 8) {
            float ss = 0.f;
            for (int w = 0; w < Ww; ++w) { float v = s_z[260 + w]; ss = fmaf(v, v, ss); }
            s_sc[3] = sqrtf(ss) + EPSf;
        } else if (tid == 16) {
            s_sc[0] = oneplus_(s_z[324]);
            s_sc[1] = sigm(s_z[457]);
            s_sc[2] = sigm(s_z[458]);
        }
        __syncthreads();  // B4

        // ---- parse vectors + usage update (OLD ww, OLD rw) ----
        if (tid < 256) {
            s_rkeyn[tid] = s_z[tid] / s_knorm[tid & 3];
            float ret = 1.f;
#pragma unroll
            for (int r = 0; r < Rr; ++r) ret *= 1.f - s_fg[r] * s_rw[tid][r];
            float u = s_usage[tid], wwo = s_ww[tid];
            s_usage[tid] = (u + wwo - u * wwo) * ret;
        }
        if (tid < Ww) {
            s_wkeyn[tid] = s_z[260 + tid] / s_sc[3];
            s_erase[tid] = sigm(s_z[325 + tid]);
            s_wvec[tid]  = s_z[389 + tid];
        }
        __syncthreads();  // B5

        // ---- P2: rank partials + wc content partials (OLD mem) ----
        {
            float ui = s_usage[n8];
            float cnt = 0.f;
            int j0 = q * 64;
#pragma unroll 8
            for (int j = j0; j < j0 + 64; ++j) {
                float uj = s_usage[j];
                if (uj < ui || (uj == ui && j < n8)) cnt += 1.f;
            }
            s_part[q*256 + n8] = cnt;
        }
        {
            float ssv = 0.f, dot = 0.f;
            int w0 = q * 16;
#pragma unroll
            for (int w = w0; w < w0 + 16; ++w) {
                float m = __half2float(memh[w*256 + n8]);
                ssv = fmaf(m, m, ssv);
                dot = fmaf(m, s_wkeyn[w], dot);
            }
            s_lp[q][n8][0] = dot;
            s_ssp[q][n8] = ssv;
        }
        __syncthreads();  // B6

        // ---- mega (wave 0): rank -> sorted -> prefix -> cp -> wc softmax -> ww ----
        if (wv == 0) {
            int rk[4]; float uu[4];
#pragma unroll
            for (int i = 0; i < 4; ++i) {
                int n = lane*4 + i;
                float c = s_part[n] + s_part[256+n] + s_part[512+n] + s_part[768+n];
                rk[i] = (int)(c + 0.5f);
                uu[i] = s_usage[n];
                s_rank[n] = rk[i];
                s_sorted[rk[i]] = uu[i];
            }
            float4 vs = ((const float4*)s_sorted)[lane];
            float p1 = vs.x*vs.y, p2 = p1*vs.z, tot = p2*vs.w;
            float incl = tot;
#pragma unroll
            for (int off = 1; off < 64; off <<= 1) {
                float tv = __shfl_up(incl, off, 64);
                if (lane >= off) incl *= tv;
            }
            float excl = __shfl_up(incl, 1, 64);
            if (lane == 0) excl = 1.f;
            float4 o; o.x = excl; o.y = excl*vs.x; o.z = excl*p1; o.w = excl*p2;
            ((float4*)s_cp)[lane] = o;

            float sims[4], mx = -1e30f;
#pragma unroll
            for (int i = 0; i < 4; ++i) {
                int n = lane*4 + i;
                float dot = s_lp[0][n][0]+s_lp[1][n][0]+s_lp[2][n][0]+s_lp[3][n][0];
                float ssv = s_ssp[0][n]+s_ssp[1][n]+s_ssp[2][n]+s_ssp[3][n];
                sims[i] = dot / (sqrtf(ssv) + EPSf) * s_sc[0];
                mx = fmaxf(mx, sims[i]);
            }
#pragma unroll
            for (int off = 32; off; off >>= 1) mx = fmaxf(mx, __shfl_xor(mx, off, 64));
            float es[4], ls = 0.f;
#pragma unroll
            for (int i = 0; i < 4; ++i) { es[i] = expf(sims[i] - mx); ls += es[i]; }
#pragma unroll
            for (int off = 32; off; off >>= 1) ls += __shfl_xor(ls, off, 64);
            float ag = s_sc[1], wg = s_sc[2], inv = 1.f / ls, lw = 0.f;
#pragma unroll
            for (int i = 0; i < 4; ++i) {
                int n = lane*4 + i;
                float alloc = (1.f - uu[i]) * s_cp[rk[i]];
                float wwn = wg * (ag * alloc + (1.f - ag) * es[i] * inv);
                s_ww[n] = wwn; lw += wwn;
            }
#pragma unroll
            for (int off = 32; off; off >>= 1) lw += __shfl_xor(lw, off, 64);
            if (lane == 0) s_red[0] = lw;
        }
        __syncthreads();  // B7

        // ---- P4: mem update (fp16 RMW) + link col pass (update + bwd partials) ----
#pragma unroll
        for (int j = 0; j < 8; ++j) {
            int i2 = tid + j*1024;
            int w = i2 >> 7, n2 = i2 & 127;
            float2 mf = __half22float2(memh2[i2]);
            float wa = s_ww[n2*2], wb = s_ww[n2*2 + 1];
            float er = s_erase[w], wvv = s_wvec[w];
            mf.x = mf.x * (1.f - wa*er) + wa*wvv;
            mf.y = mf.y * (1.f - wb*er) + wb*wvv;
            memh2[i2] = __floats2half2_rn(mf.x, mf.y);
        }
        {
            float pt = s_prec[n8], wwc = s_ww[n8];
            float b0 = 0.f, b1_ = 0.f, b2_ = 0.f, b3_ = 0.f;
            int k0 = q * 64;
#pragma unroll 4
            for (int k = k0; k < k0 + 64; ++k) {
                float lold = __half2float(linkh[k*256 + n8]);
                float wk = s_ww[k];
                float lnew = (1.f - wk - wwc) * lold + wk * pt;
                if (k == n8) lnew = 0.f;
                linkh[k*256 + n8] = __float2half(lnew);
                float4 r4 = rw4[k];
                b0  = fmaf(lnew, r4.x, b0);
                b1_ = fmaf(lnew, r4.y, b1_);
                b2_ = fmaf(lnew, r4.z, b2_);
                b3_ = fmaf(lnew, r4.w, b3_);
            }
            s_lp[q][n8][0] = b0; s_lp[q][n8][1] = b1_;
            s_lp[q][n8][2] = b2_; s_lp[q][n8][3] = b3_;
        }
        __syncthreads();  // B8

        // ---- P5: bwd reduce + prec update + fwd compute (regs) ----
        float bwv = s_lp[0][n8][rr] + s_lp[1][n8][rr] + s_lp[2][n8][rr] + s_lp[3][n8][rr];
        if (tid < 256) s_prec[tid] = (1.f - s_red[0]) * s_prec[tid] + s_ww[tid];
        float f0 = 0.f, f1 = 0.f, f2 = 0.f, f3 = 0.f;
        {
            const __half2* lrow = (const __half2*)(linkh + n8*256) + q*32;
#pragma unroll 4
            for (int m2 = 0; m2 < 32; ++m2) {
                float2 l = __half22float2(lrow[m2]);
                int m = q*64 + 2*m2;
                float4 wA = rw4[m], wB = rw4[m+1];
                f0 = fmaf(l.x, wA.x, f0); f1 = fmaf(l.x, wA.y, f1);
                f2 = fmaf(l.x, wA.z, f2); f3 = fmaf(l.x, wA.w, f3);
                f0 = fmaf(l.y, wB.x, f0); f1 = fmaf(l.y, wB.y, f1);
                f2 = fmaf(l.y, wB.z, f2); f3 = fmaf(l.y, wB.w, f3);
            }
        }
        __syncthreads();  // B9

        // ---- P6: publish fwd partials ----
        s_lp[q][n8][0] = f0; s_lp[q][n8][1] = f1;
        s_lp[q][n8][2] = f2; s_lp[q][n8][3] = f3;
        __syncthreads();  // B10

        // ---- P7: fwd reduce + read content (NEW mem, direct column read) ----
        float fwv = s_lp[0][n8][rr] + s_lp[1][n8][rr] + s_lp[2][n8][rr] + s_lp[3][n8][rr];
        float e_rc;
        {
            float ssv = 0.f, dv = 0.f;
#pragma unroll 4
            for (int w = 0; w < Ww; ++w) {
                float m = __half2float(memh[w*256 + n8]);
                ssv = fmaf(m, m, ssv);
                dv = fmaf(m, s_rkeyn[w*4 + rr], dv);
            }
            float sim = dv / (sqrtf(ssv) + EPSf) * s_rstr[rr];
            float mx = sim;
#pragma unroll
            for (int o = 32; o; o >>= 1) mx = fmaxf(mx, __shfl_xor(mx, o, 64));
            if (lane == 0) s_red[wv] = mx;
            __syncthreads();  // B11
            mx = fmaxf(fmaxf(s_red[rr*4+0], s_red[rr*4+1]), fmaxf(s_red[rr*4+2], s_red[rr*4+3]));
            e_rc = expf(sim - mx);
            float s = e_rc;
#pragma unroll
            for (int o = 32; o; o >>= 1) s += __shfl_xor(s, o, 64);
            if (lane == 0) s_red[16 + wv] = s;
        }
        __syncthreads();  // B12

        // ---- P9: rc + rw_new ----
        {
            float sm = (s_red[16+rr*4+0] + s_red[16+rr*4+1]) + (s_red[16+rr*4+2] + s_red[16+rr*4+3]);
            float rc = e_rc / sm;
            s_rw[n8][rr] = bwv * s_rmode[0][rr] + rc * s_rmode[1][rr] + fwv * s_rmode[2][rr];
        }
        __syncthreads();  // B13

        // ---- P10: rvec[w][r] = sum_n mem[w][n]*rw[n][r]; 4-lane K-split ----
        {
            int o = tid >> 2, c = tid & 3;
            int w = o >> 2, r = o & 3;
            float a = 0.f;
#pragma unroll 4
            for (int j = 0; j < 64; ++j) {
                int n = c*64 + j;
                a = fmaf(__half2float(memh[w*256 + n]), s_rw[n][r], a);
            }
            a += __shfl_xor(a, 1, 64); a += __shfl_xor(a, 2, 64);
            if (c == 0) s_rvec[o] = a;
        }
        __syncthreads();  // B14

        // ---- P11: out = nn @ W_out + rvec @ W_mem_out; 16-lane K-split ----
        {
            const __half2* wsrc = (c4 < 8) ? (wp + WOUTOFF + (c4*16)*64 + o4)
                                           : (wp + WMEMOFF + ((c4-8)*16)*64 + o4);
            const float* vsrc = (c4 < 8) ? (s_nn + c4*32) : (((const float*)s_rvec) + (c4-8)*32);
            float acc = 0.f;
#pragma unroll
            for (int j = 0; j < 16; ++j) {
                float2 wv2 = __half22float2(wsrc[j*64]);
                float2 vv = *(const float2*)&vsrc[j*2];
                acc = fmaf(vv.x, wv2.x, acc);
                acc = fmaf(vv.y, wv2.y, acc);
            }
#pragma unroll
            for (int off = 1; off < 16; off <<= 1) acc += __shfl_xor(acc, off, 64);
            if (c4 == 0) out[(t*Bb + b)*OUTd + o4] = acc;
        }
        // next-step controller input
        if (tid < 256) s_ctrl[64 + tid] = s_rvec[tid];
        else if (tid >= 256 && tid < 320) {
            if (t + 1 < Tt) s_ctrl[tid - 256] = x[((t+1)*Bb + b)*INd + (tid - 256)];
        }
        // loop-top barrier covers these writes
    }
}

extern "C" void kernel_launch(void* const* d_in, const int* in_sizes, int n_in,
                              void* d_out, int out_size, void* d_ws, size_t ws_size,
                              hipStream_t stream) {
    const float* x    = (const float*)d_in[0];
    const float* W1   = (const float*)d_in[1];
    const float* b1   = (const float*)d_in[2];
    const float* W2   = (const float*)d_in[3];
    const float* b2   = (const float*)d_in[4];
    const float* Wif  = (const float*)d_in[5];
    const float* bif  = (const float*)d_in[6];
    const float* Wout = (const float*)d_in[7];
    const float* Wmem = (const float*)d_in[8];
    float* out = (float*)d_out;

    // ws layout: [0, 601600) packed half2 weights; then mem fp16 (16*32KB);
    // then link fp16 (16*128KB). Total ~3.1 MB.
    char* ws = (char*)d_ws;
    __half2* wp   = (__half2*)ws;
    __half* memg  = (__half*)(ws + 601600);
    __half* linkg = (__half*)(ws + 601600 + 524288);

    convert_weights<<<dim3((WTOT + 255)/256), dim3(256), 0, stream>>>(W1, W2, Wif, Wout, Wmem, wp);
    dnc_kernel<<<dim3(Bb), dim3(1024), 0, stream>>>(x, b1, b2, bif, wp, memg, linkg, out);
}

// Round 4
// 4269.640 us; speedup vs baseline: 1.6626x; 1.6626x over previous
//
#include <hip/hip_runtime.h>
#include <hip/hip_fp16.h>
#include <math.h>

#define Tt 64
#define Bb 16
#define Nn 256
#define Ww 64
#define Rr 4
#define INd 64
#define OUTd 64
#define IFS 471
#define EPSf 1e-6f

// packed half2 weight layout offsets (in half2 units), pairs along K
#define W1OFF   0        // 160*256
#define W2OFF   40960    // 128*256
#define WIFOFF  73728    // 128*471
#define WOUTOFF 134016   // 128*64
#define WMEMOFF 142208   // 128*64
#define WTOT    150400

// link: 256 rows x 129 dwords (258 halfs, 256 used + 2 pad) -> 2-way-max banks both ways
#define LROW    129                  // half2 (dword) stride per row
#define LINKB   (256 * LROW * 4)     // 132096 B
#define SCRB    16384                // scratch bytes (4096 floats / 8192 halfs)
#define FIXF    3664                 // fixed float count
#define SMEM_MAIN (LINKB + SCRB + FIXF * 4)   // 163136 <= 163840
#define SMEM_FB   (SCRB + FIXF * 4)           // 31040

__device__ __forceinline__ float sigm(float x) { return 1.f / (1.f + expf(-x)); }
__device__ __forceinline__ float oneplus_(float x) {
    return 1.f + fmaxf(x, 0.f) + log1pf(expf(-fabsf(x)));
}
__device__ __forceinline__ float wsum(float v) {
#pragma unroll
    for (int o = 32; o; o >>= 1) v += __shfl_xor(v, o, 64);
    return v;
}
__device__ __forceinline__ float wmaxr(float v) {
#pragma unroll
    for (int o = 32; o; o >>= 1) v = fmaxf(v, __shfl_xor(v, o, 64));
    return v;
}

// ---- converter: fp32 weights -> packed half2 (pairs along K) ----
__global__ void convert_weights(const float* __restrict__ W1, const float* __restrict__ W2,
                                const float* __restrict__ Wif, const float* __restrict__ Wout,
                                const float* __restrict__ Wmem, __half2* __restrict__ wp) {
    int i = blockIdx.x * blockDim.x + threadIdx.x;
    if (i >= WTOT) return;
    float a, b;
    if (i < W2OFF)        { int r = i;           int k2 = r >> 8, n = r & 255; a = W1[(2*k2)*256+n];  b = W1[(2*k2+1)*256+n]; }
    else if (i < WIFOFF)  { int r = i - W2OFF;   int k2 = r >> 8, n = r & 255; a = W2[(2*k2)*256+n];  b = W2[(2*k2+1)*256+n]; }
    else if (i < WOUTOFF) { int r = i - WIFOFF;  int k2 = r / IFS, o = r - IFS*k2; a = Wif[(2*k2)*IFS+o]; b = Wif[(2*k2+1)*IFS+o]; }
    else if (i < WMEMOFF) { int r = i - WOUTOFF; int k2 = r >> 6, n = r & 63;  a = Wout[(2*k2)*64+n]; b = Wout[(2*k2+1)*64+n]; }
    else                  { int r = i - WMEMOFF; int k2 = r >> 6, n = r & 63;  a = Wmem[(2*k2)*64+n]; b = Wmem[(2*k2+1)*64+n]; }
    wp[i] = __floats2half2_rn(a, b);
}

// One block (1024 threads, 16 waves) per batch element; whole T=64 scan inside.
// LLINK: temporal-link matrix in LDS (needs 160KB opt-in); else in global ws.
template <bool LLINK>
__global__ __launch_bounds__(1024) void dnc_kernel(
    const float* __restrict__ x, const float* __restrict__ b1,
    const float* __restrict__ b2, const float* __restrict__ bif,
    const __half2* __restrict__ wp,
    __half* __restrict__ memg,      // per batch 64*256 halves, [w][n]
    __half2* __restrict__ linkg,    // fallback link, per batch 256*LROW half2
    float* __restrict__ out)
{
    extern __shared__ __align__(16) char smem[];
    const int b = blockIdx.x;
    const int tid = threadIdx.x;
    const int lane = tid & 63;
    const int wv = tid >> 6;

    __half2* l2p = (__half2*)smem;                                   // LDS link (main)
    __half2* gl2 = linkg + (size_t)b * (256 * LROW);                 // global link (fb)
    float* scr  = (float*)(smem + (LLINK ? LINKB : 0));              // 4096 floats
    __half* scrh = (__half*)scr;                                     // fp16 partial view
    float* fx   = (float*)((char*)scr + SCRB);                       // fixed floats

    float* s_ctrl  = fx + 0;      // 320
    float* s_h     = fx + 320;    // 256
    float* s_nn    = fx + 576;    // 256
    float* s_z     = fx + 832;    // 472
    float* s_usage = fx + 1304;   // 256
    float* s_ww    = fx + 1560;   // 256
    float* s_prec  = fx + 1816;   // 256
    float* s_rw    = fx + 2072;   // 256*4 (16B aligned)
    float* s_wcdot = fx + 3096;   // 256
    float* s_wcss  = fx + 3352;   // 256
    float* s_knorm = fx + 3608;   // 4
    float* s_rstr  = fx + 3612;   // 4
    float* s_rmode = fx + 3616;   // 12 [mode*4+r]
    float* s_sc    = fx + 3628;   // 4: 0 wstr, 1 agate, 2 wgate, 3 wkeynorm
    float* s_red   = fx + 3632;   // 32
    float* s_srt   = scr + 1024;  // 256 (mega only)
    float* s_cp    = scr + 1280;  // 256 (mega only)
    float* s_rvec  = scr + 1536;  // 256 (phase 16..18)

    const float4* rw4 = (const float4*)s_rw;
    __half*  memh  = memg + (size_t)b * (Ww * Nn);
    __half2* memh2 = (__half2*)memh;

    auto lread = [&](int idx) -> __half2 {
        if constexpr (LLINK) return l2p[idx]; else return gl2[idx];
    };
    auto lwrite = [&](int idx, __half2 v) {
        if constexpr (LLINK) l2p[idx] = v; else gl2[idx] = v;
    };

    // ---- init (ws/LDS poisoned before every launch) ----
    {
        __half2 z2 = __floats2half2_rn(0.f, 0.f);
        for (int i = tid; i < 256 * LROW; i += 1024) lwrite(i, z2);
        __half2 e2 = __floats2half2_rn(EPSf, EPSf);
#pragma unroll
        for (int j = 0; j < 8; ++j) memh2[tid + j * 1024] = e2;
    }
    if (tid < 256) {
        s_usage[tid] = 0.f; s_ww[tid] = 0.f; s_prec[tid] = 0.f;
        s_rw[tid*4+0] = 0.f; s_rw[tid*4+1] = 0.f; s_rw[tid*4+2] = 0.f; s_rw[tid*4+3] = 0.f;
    }
    if (tid < 64) s_ctrl[tid] = x[b * INd + tid];
    else if (tid < 320) s_ctrl[tid] = 0.f;

    for (int t = 0; t < Tt; ++t) {
        __syncthreads();  // B0

        // ---- P1: GEMV1 partials: h-pre = ctrl(320) @ W1 ; K-split 4 (wave-uniform) ----
        {
            int kc = wv >> 2, o = (wv & 3) * 64 + lane;
            const __half2* wP = wp + W1OFF + kc * 40 * 256 + o;
            float a[8] = {0,0,0,0,0,0,0,0};
#pragma unroll
            for (int j0 = 0; j0 < 40; j0 += 8) {
                __half2 hh[8];
#pragma unroll
                for (int u = 0; u < 8; ++u) hh[u] = wP[(j0 + u) * 256];
#pragma unroll
                for (int u = 0; u < 8; ++u) {
                    float2 wf = __half22float2(hh[u]);
                    int k2 = kc * 40 + j0 + u;
                    a[u] = fmaf(s_ctrl[2*k2], wf.x, fmaf(s_ctrl[2*k2+1], wf.y, a[u]));
                }
            }
            scr[kc * 256 + o] = ((a[0]+a[1])+(a[2]+a[3])) + ((a[4]+a[5])+(a[6]+a[7]));
        }
        __syncthreads();  // B1
        if (tid < 256)
            s_h[tid] = tanhf(b1[tid] + ((scr[tid] + scr[256+tid]) + (scr[512+tid] + scr[768+tid])));
        __syncthreads();  // B2

        // ---- P3: GEMV2: nn-pre = h @ W2 ----
        {
            int kc = wv >> 2, o = (wv & 3) * 64 + lane;
            const __half2* wP = wp + W2OFF + kc * 32 * 256 + o;
            float a[8] = {0,0,0,0,0,0,0,0};
#pragma unroll
            for (int j0 = 0; j0 < 32; j0 += 8) {
                __half2 hh[8];
#pragma unroll
                for (int u = 0; u < 8; ++u) hh[u] = wP[(j0 + u) * 256];
#pragma unroll
                for (int u = 0; u < 8; ++u) {
                    float2 wf = __half22float2(hh[u]);
                    int k2 = kc * 32 + j0 + u;
                    a[u] = fmaf(s_h[2*k2], wf.x, fmaf(s_h[2*k2+1], wf.y, a[u]));
                }
            }
            scr[kc * 256 + o] = ((a[0]+a[1])+(a[2]+a[3])) + ((a[4]+a[5])+(a[6]+a[7]));
        }
        __syncthreads();  // B3
        if (tid < 256)
            s_nn[tid] = tanhf(b2[tid] + ((scr[tid] + scr[256+tid]) + (scr[512+tid] + scr[768+tid])));
        __syncthreads();  // B4

        // ---- P5: GEMV3: z-pre = nn @ W_if (471 cols); K-split 2 (wave-uniform) ----
        {
            int kc = wv >> 3, o = (wv & 7) * 64 + lane;
            if (o < IFS) {
                const __half2* wP = wp + WIFOFF + kc * 64 * IFS + o;
                float a[8] = {0,0,0,0,0,0,0,0};
#pragma unroll
                for (int j0 = 0; j0 < 64; j0 += 8) {
                    __half2 hh[8];
#pragma unroll
                    for (int u = 0; u < 8; ++u) hh[u] = wP[(j0 + u) * IFS];
#pragma unroll
                    for (int u = 0; u < 8; ++u) {
                        float2 wf = __half22float2(hh[u]);
                        int k2 = kc * 64 + j0 + u;
                        a[u] = fmaf(s_nn[2*k2], wf.x, fmaf(s_nn[2*k2+1], wf.y, a[u]));
                    }
                }
                scr[kc * 512 + o] = ((a[0]+a[1])+(a[2]+a[3])) + ((a[4]+a[5])+(a[6]+a[7]));
            }
        }
        __syncthreads();  // B5
        if (tid < IFS) s_z[tid] = bif[tid] + scr[tid] + scr[512 + tid];
        __syncthreads();  // B6

        // ---- P7: scalars + usage update + wc raw partials (merged) ----
        if (wv < 4) {               // read-key norms, r = wv
            float vz = s_z[lane * 4 + wv];
            float s = wsum(vz * vz);
            if (lane == 0) s_knorm[wv] = sqrtf(s) + EPSf;
        } else if (wv == 4) {       // write-key norm
            float vz = s_z[260 + lane];
            float s = wsum(vz * vz);
            if (lane == 0) s_sc[3] = sqrtf(s) + EPSf;
        } else if (wv == 5) {       // small scalars
            if (lane < 4) s_rstr[lane] = oneplus_(s_z[256 + lane]);
            else if (lane >= 8 && lane < 12) {
                int r = lane - 8;
                float a = s_z[459+r], bm = s_z[463+r], c = s_z[467+r];
                float mx = fmaxf(a, fmaxf(bm, c));
                float ea = expf(a-mx), eb = expf(bm-mx), ec = expf(c-mx);
                float inv = 1.f / ((ea+eb)+ec);
                s_rmode[0*4+r] = ea*inv; s_rmode[1*4+r] = eb*inv; s_rmode[2*4+r] = ec*inv;
            } else if (lane == 16) s_sc[0] = oneplus_(s_z[324]);
            else if (lane == 17) s_sc[1] = sigm(s_z[457]);
            else if (lane == 18) s_sc[2] = sigm(s_z[458]);
        } else if (wv >= 8 && wv < 12) {   // usage update (OLD ww, OLD rw)
            int n = tid - 512;
            float ret = 1.f;
#pragma unroll
            for (int r = 0; r < 4; ++r) {
                float fg = sigm(s_z[453 + r]);
                ret *= 1.f - fg * s_rw[n*4 + r];
            }
            float u = s_usage[n], wwo = s_ww[n];
            s_usage[n] = (u + wwo - u * wwo) * ret;
        } else if (wv >= 12) {      // wc raw dot/ss on OLD mem (coalesced columns)
            int n = tid - 768;
            float dot = 0.f, ssv = 0.f;
#pragma unroll 8
            for (int w = 0; w < Ww; ++w) {
                float m = __half2float(memh[w * 256 + n]);
                ssv = fmaf(m, m, ssv);
                dot = fmaf(m, s_z[260 + w], dot);
            }
            s_wcdot[n] = dot; s_wcss[n] = ssv;
        }
        __syncthreads();  // B7

        // ---- P8: rank partials (stable ascending argsort by counting) ----
        {
            int q = tid >> 8, n = tid & 255;
            float un = s_usage[n];
            float cnt = 0.f;
            int j0 = q * 64;
#pragma unroll 8
            for (int j = j0; j < j0 + 64; ++j) {
                float uj = s_usage[j];
                if (uj < un || (uj == un && j < n)) cnt += 1.f;
            }
            scr[q * 256 + n] = cnt;
        }
        __syncthreads();  // B8

        // ---- P9: mega (wave 0): rank -> sorted -> prefix-prod -> alloc -> wc softmax -> ww ----
        if (wv == 0) {
            int rk[4]; float uu[4];
#pragma unroll
            for (int i = 0; i < 4; ++i) {
                int n = lane * 4 + i;
                float c = scr[n] + scr[256+n] + scr[512+n] + scr[768+n];
                rk[i] = (int)(c + 0.5f);
                uu[i] = s_usage[n];
                s_srt[rk[i]] = uu[i];
            }
            float4 vs = ((const float4*)s_srt)[lane];
            float p1 = vs.x * vs.y, p2 = p1 * vs.z, tot = p2 * vs.w;
            float incl = tot;
#pragma unroll
            for (int off = 1; off < 64; off <<= 1) {
                float tv = __shfl_up(incl, off, 64);
                if (lane >= off) incl *= tv;
            }
            float excl = __shfl_up(incl, 1, 64);
            if (lane == 0) excl = 1.f;
            float4 o4v; o4v.x = excl; o4v.y = excl*vs.x; o4v.z = excl*p1; o4v.w = excl*p2;
            ((float4*)s_cp)[lane] = o4v;

            float sims[4], mx = -1e30f;
#pragma unroll
            for (int i = 0; i < 4; ++i) {
                int n = lane * 4 + i;
                sims[i] = s_wcdot[n] / ((sqrtf(s_wcss[n]) + EPSf) * s_sc[3]) * s_sc[0];
                mx = fmaxf(mx, sims[i]);
            }
            mx = wmaxr(mx);
            float es[4], ls = 0.f;
#pragma unroll
            for (int i = 0; i < 4; ++i) { es[i] = expf(sims[i] - mx); ls += es[i]; }
            ls = wsum(ls);
            float ag = s_sc[1], wg = s_sc[2], inv = 1.f / ls, lw = 0.f;
#pragma unroll
            for (int i = 0; i < 4; ++i) {
                int n = lane * 4 + i;
                float alloc = (1.f - uu[i]) * s_cp[rk[i]];
                float wwn = wg * (ag * alloc + (1.f - ag) * es[i] * inv);
                s_ww[n] = wwn; lw += wwn;
            }
            lw = wsum(lw);
            if (lane == 0) s_red[0] = lw;   // sum(ww)
        }
        __syncthreads();  // B9

        // ---- P10: link column-pair pass (update + bwd partials) || mem fp16 RMW ----
        if (tid < 512) {
            int kc = tid >> 7, p = tid & 127;
            int c0 = 2 * p, c1 = c0 + 1;
            float wwc0 = s_ww[c0], wwc1 = s_ww[c1];
            float pt0 = s_prec[c0], pt1 = s_prec[c1];
            float acc[8] = {0,0,0,0,0,0,0,0};
            int k0 = kc * 64;
#pragma unroll 8
            for (int k = k0; k < k0 + 64; ++k) {
                float2 lf = __half22float2(lread(k * LROW + p));
                float wk = s_ww[k];
                float l0 = (1.f - wk - wwc0) * lf.x + wk * pt0;
                float l1 = (1.f - wk - wwc1) * lf.y + wk * pt1;
                if (k == c0) l0 = 0.f;
                if (k == c1) l1 = 0.f;
                lwrite(k * LROW + p, __floats2half2_rn(l0, l1));
                float4 r4v = rw4[k];
                acc[0] = fmaf(l0, r4v.x, acc[0]); acc[1] = fmaf(l0, r4v.y, acc[1]);
                acc[2] = fmaf(l0, r4v.z, acc[2]); acc[3] = fmaf(l0, r4v.w, acc[3]);
                acc[4] = fmaf(l1, r4v.x, acc[4]); acc[5] = fmaf(l1, r4v.y, acc[5]);
                acc[6] = fmaf(l1, r4v.z, acc[6]); acc[7] = fmaf(l1, r4v.w, acc[7]);
            }
            __half2* bp = (__half2*)scrh + (kc * 128 + p) * 4;   // bwd partials [0:8KB)
            bp[0] = __floats2half2_rn(acc[0], acc[1]);
            bp[1] = __floats2half2_rn(acc[2], acc[3]);
            bp[2] = __floats2half2_rn(acc[4], acc[5]);
            bp[3] = __floats2half2_rn(acc[6], acc[7]);
        } else {
            int t0 = tid - 512;
#pragma unroll 4
            for (int j = 0; j < 16; ++j) {
                int i2 = t0 + j * 512;
                int w = i2 >> 7, n2 = i2 & 127;
                float er = sigm(s_z[325 + w]);
                float wvv = s_z[389 + w];
                float2 mf = __half22float2(memh2[i2]);
                float wa = s_ww[2*n2], wb = s_ww[2*n2 + 1];
                mf.x = mf.x * (1.f - wa * er) + wa * wvv;
                mf.y = mf.y * (1.f - wb * er) + wb * wvv;
                memh2[i2] = __floats2half2_rn(mf.x, mf.y);
            }
        }
        __syncthreads();  // B10

        // ---- P11: fwd row pass (link_new @ rw_old) + prec update ----
        {
            int q = tid >> 8, n8 = tid & 255;
            float f0 = 0.f, f1 = 0.f, f2 = 0.f, f3 = 0.f;
            int m0 = q * 64;
#pragma unroll 8
            for (int j = 0; j < 32; ++j) {
                float2 lf = __half22float2(lread(n8 * LROW + m0 / 2 + j));
                int m = m0 + 2 * j;
                float4 wA = rw4[m], wB = rw4[m + 1];
                f0 = fmaf(lf.x, wA.x, fmaf(lf.y, wB.x, f0));
                f1 = fmaf(lf.x, wA.y, fmaf(lf.y, wB.y, f1));
                f2 = fmaf(lf.x, wA.z, fmaf(lf.y, wB.z, f2));
                f3 = fmaf(lf.x, wA.w, fmaf(lf.y, wB.w, f3));
            }
            __half2* fp2 = (__half2*)(scrh + 4096) + (q * 256 + n8) * 2;  // fwd partials [8KB:16KB)
            fp2[0] = __floats2half2_rn(f0, f1);
            fp2[1] = __floats2half2_rn(f2, f3);
            if (q == 0) s_prec[n8] = (1.f - s_red[0]) * s_prec[n8] + s_ww[n8];
        }
        __syncthreads();  // B11

        // ---- P12: rc content sim (NEW mem) + bwd/fwd reduce ----
        int rr = tid >> 8, n8c = tid & 255;
        float bwv = 0.f, fwv = 0.f, e_rc = 0.f, sim;
        {
#pragma unroll
            for (int kc = 0; kc < 4; ++kc)
                bwv += __half2float(scrh[(kc * 128 + (n8c >> 1)) * 8 + (n8c & 1) * 4 + rr]);
#pragma unroll
            for (int qq = 0; qq < 4; ++qq)
                fwv += __half2float(scrh[4096 + (qq * 256 + n8c) * 4 + rr]);
            float ssv = 0.f, dv = 0.f;
#pragma unroll 8
            for (int w = 0; w < Ww; ++w) {
                float m = __half2float(memh[w * 256 + n8c]);
                ssv = fmaf(m, m, ssv);
                dv = fmaf(m, s_z[w * 4 + rr], dv);
            }
            sim = dv / ((sqrtf(ssv) + EPSf) * s_knorm[rr]) * s_rstr[rr];
            float mx = wmaxr(sim);
            if (lane == 0) s_red[wv] = mx;
        }
        __syncthreads();  // B12
        {
            float mx = fmaxf(fmaxf(s_red[rr*4+0], s_red[rr*4+1]), fmaxf(s_red[rr*4+2], s_red[rr*4+3]));
            e_rc = expf(sim - mx);
            float s = wsum(e_rc);
            if (lane == 0) s_red[16 + wv] = s;
        }
        __syncthreads();  // B13
        {
            float sm = (s_red[16+rr*4+0] + s_red[16+rr*4+1]) + (s_red[16+rr*4+2] + s_red[16+rr*4+3]);
            float rc = e_rc / sm;
            s_rw[n8c*4 + rr] = bwv * s_rmode[0*4+rr] + rc * s_rmode[1*4+rr] + fwv * s_rmode[2*4+rr];
        }
        __syncthreads();  // B14

        // ---- P15: rvec partials: rvec[w][r] = sum_n mem[w][n]*rw[n][r]; K-split 4 ----
        {
            int kc = tid >> 8, o = tid & 255, w = o >> 2, r = o & 3;
            const __half* mw = memh + w * 256 + kc * 64;
            float a = 0.f;
#pragma unroll 8
            for (int j = 0; j < 64; ++j)
                a = fmaf(__half2float(mw[j]), s_rw[(kc * 64 + j) * 4 + r], a);
            scr[kc * 256 + o] = a;
        }
        __syncthreads();  // B15
        if (tid < 256)
            s_rvec[tid] = (scr[tid] + scr[256+tid]) + (scr[512+tid] + scr[768+tid]);
        else if (tid >= 512 && tid < 576) {
            if (t + 1 < Tt) s_ctrl[tid - 512] = x[((t + 1) * Bb + b) * INd + (tid - 512)];
        }
        __syncthreads();  // B16

        // ---- P17: out = nn @ W_out + rvec @ W_mem_out; wave-uniform K-split 16 ----
        {
            int c4 = wv, o4 = lane;
            const float* vsrc = (c4 < 8) ? (s_nn + c4 * 32) : (s_rvec + (c4 - 8) * 32);
            const __half2* wsrc = wp + ((c4 < 8) ? (WOUTOFF + c4 * 16 * 64)
                                                 : (WMEMOFF + (c4 - 8) * 16 * 64)) + o4;
            float a = 0.f;
#pragma unroll
            for (int j = 0; j < 16; ++j) {
                float2 wf = __half22float2(wsrc[j * 64]);
                a = fmaf(vsrc[2*j], wf.x, fmaf(vsrc[2*j+1], wf.y, a));
            }
            scr[c4 * 64 + o4] = a;
        }
        __syncthreads();  // B17
        if (tid < 64) {
            float s = 0.f;
#pragma unroll
            for (int g = 0; g < 16; ++g) s += scr[g * 64 + tid];
            out[(t * Bb + b) * OUTd + tid] = s;
        } else if (tid >= 64 && tid < 320) {
            s_ctrl[tid] = s_rvec[tid - 64];   // next-step controller input
        }
        // loop-top barrier covers these writes
    }
}

extern "C" void kernel_launch(void* const* d_in, const int* in_sizes, int n_in,
                              void* d_out, int out_size, void* d_ws, size_t ws_size,
                              hipStream_t stream) {
    const float* x    = (const float*)d_in[0];
    const float* W1   = (const float*)d_in[1];
    const float* b1   = (const float*)d_in[2];
    const float* W2   = (const float*)d_in[3];
    const float* b2   = (const float*)d_in[4];
    const float* Wif  = (const float*)d_in[5];
    const float* bif  = (const float*)d_in[6];
    const float* Wout = (const float*)d_in[7];
    const float* Wmem = (const float*)d_in[8];
    float* out = (float*)d_out;

    // ws layout: [0,601600) packed half2 weights; [601600,+512KB) mem fp16;
    // then fallback link region 16*132096 = 2113536 B. Total ~3.1 MB.
    char* ws = (char*)d_ws;
    __half2* wp    = (__half2*)ws;
    __half*  memg  = (__half*)(ws + 601600);
    __half2* linkg = (__half2*)(ws + 601600 + 524288);

    convert_weights<<<dim3((WTOT + 255) / 256), dim3(256), 0, stream>>>(W1, W2, Wif, Wout, Wmem, wp);

    hipError_t rc = hipFuncSetAttribute(
        reinterpret_cast<const void*>(&dnc_kernel<true>),
        hipFuncAttributeMaxDynamicSharedMemorySize, SMEM_MAIN);
    if (rc == hipSuccess) {
        dnc_kernel<true><<<dim3(Bb), dim3(1024), SMEM_MAIN, stream>>>(
            x, b1, b2, bif, wp, memg, linkg, out);
    } else {
        dnc_kernel<false><<<dim3(Bb), dim3(1024), SMEM_FB, stream>>>(
            x, b1, b2, bif, wp, memg, linkg, out);
    }
}